// Round 3
// baseline (302.494 us; speedup 1.0000x reference)
//
#include <hip/hip_runtime.h>

// PillarMaxPooling R3: moment-based BN stats + linked-list gather-max.
// K1 pass1: per point (once): build per-pillar linked list (1 atomicExch/pt),
//   accumulate 77 moments of g (11 first + 66 second) -> wave butterfly ->
//   block stage -> 77 atomicAdd/block. NO matmul in pass 1.
// K2 finalize: mean[c]=m1.W[:,c], E[h2][c]=W[:,c]^T M2 W[:,c] -> affine sc/bi.
// K3 pool: half-wave per pillar (lane=channel), walk chain with broadcast
//   loads, h=g.W -> relu(h*sc+bi) -> running max -> ONE coalesced store.
//   No output atomics (R2's 25.6M atomicMax was ~145us), no LDS.

#define CMLP 32
#define BN_EPS 1e-3f
#define PSIZE 0.075f
#define XMIN -54.0f
#define YMIN -54.0f
#define CZ   -1.0f   // 0.5*(Z_MIN+Z_MAX)
#define NMOM 77      // 11 first + 66 upper-tri second moments

__global__ void __launch_bounds__(256) pass1_kernel(
    const float* __restrict__ xyz, const float* __restrict__ ptf,
    const int* __restrict__ pil, const int* __restrict__ sidx,
    int* __restrict__ head, int* __restrict__ next,
    float* __restrict__ stats, int N) {
  float mom[NMOM];
#pragma unroll
  for (int k = 0; k < NMOM; k++) mom[k] = 0.f;
  const int stride = gridDim.x * blockDim.x;
  for (int p = blockIdx.x * blockDim.x + threadIdx.x; p < N; p += stride) {
    int m = sidx[p];
    next[p] = atomicExch(&head[m], p);  // lock-free list prepend
    float cx = fmaf((float)pil[3 * m + 2] + 0.5f, PSIZE, XMIN);
    float cy = fmaf((float)pil[3 * m + 1] + 0.5f, PSIZE, YMIN);
    float x = xyz[3 * p], y = xyz[3 * p + 1], z = xyz[3 * p + 2];
    float g[11];
    g[0] = x - cx; g[1] = y - cy; g[2] = z - CZ;
    g[3] = x; g[4] = y; g[5] = z;
#pragma unroll
    for (int k = 0; k < 5; k++) g[6 + k] = ptf[5 * p + k];
    int t = 0;
#pragma unroll
    for (int i = 0; i < 11; i++) { mom[t] += g[i]; t++; }
#pragma unroll
    for (int i = 0; i < 11; i++)
#pragma unroll
      for (int j = i; j < 11; j++) { mom[t] = fmaf(g[i], g[j], mom[t]); t++; }
  }
  // per-wave butterfly reduction (all static indices -> stays in VGPRs)
#pragma unroll
  for (int d = 1; d < 64; d <<= 1)
#pragma unroll
    for (int k = 0; k < NMOM; k++) mom[k] += __shfl_xor(mom[k], d);
  __shared__ float smom[4 * NMOM];
  const int wave = threadIdx.x >> 6;
  if ((threadIdx.x & 63) == 0) {
#pragma unroll
    for (int k = 0; k < NMOM; k++) smom[wave * NMOM + k] = mom[k];
  }
  __syncthreads();
  if (threadIdx.x < NMOM) {
    float s = smom[threadIdx.x] + smom[NMOM + threadIdx.x] +
              smom[2 * NMOM + threadIdx.x] + smom[3 * NMOM + threadIdx.x];
    atomicAdd(&stats[threadIdx.x], s);  // 77 atomics per block (1024 blocks)
  }
}

__global__ void finalize_kernel(const float* __restrict__ gamma,
                                const float* __restrict__ beta,
                                const float* __restrict__ W1,
                                float* __restrict__ stats, float invN) {
  int c = threadIdx.x;
  if (c < CMLP) {
    float wv[11];
#pragma unroll
    for (int k = 0; k < 11; k++) wv[k] = W1[k * CMLP + c];
    float mean = 0.f;
#pragma unroll
    for (int k = 0; k < 11; k++) mean = fmaf(wv[k], stats[k], mean);
    mean *= invN;
    float e2 = 0.f;
    int t = 11;
#pragma unroll
    for (int i = 0; i < 11; i++)
#pragma unroll
      for (int j = i; j < 11; j++) {
        float coef = (i == j) ? 1.f : 2.f;
        e2 = fmaf(coef * wv[i] * wv[j], stats[t], e2);
        t++;
      }
    e2 *= invN;
    float var = e2 - mean * mean;                 // biased, like jnp.var
    float sc = gamma[c] * rsqrtf(var + BN_EPS);
    stats[80 + c] = sc;                           // scale
    stats[112 + c] = beta[c] - mean * sc;         // bias
  }
}

__global__ void __launch_bounds__(256) pool_kernel(
    const float* __restrict__ xyz, const float* __restrict__ ptf,
    const float* __restrict__ W1, const int* __restrict__ pil,
    const int* __restrict__ head, const int* __restrict__ next,
    const float* __restrict__ affine, float* __restrict__ out, int M) {
  const int tid = threadIdx.x;
  const int c = tid & 31;
  const int wave = blockIdx.x * 4 + (tid >> 6);
  const int m = wave * 2 + ((tid >> 5) & 1);  // half-wave per pillar
  float w[11];
#pragma unroll
  for (int k = 0; k < 11; k++) w[k] = W1[k * CMLP + c];
  const float sc = affine[c];
  const float bi = affine[CMLP + c];
  float v = 0.f;  // relu floor + empty-pillar value
  float cx = 0.f, cy = 0.f;
  int p = -1;
  if (m < M) {
    p = head[m];
    cx = fmaf((float)pil[3 * m + 2] + 0.5f, PSIZE, XMIN);
    cy = fmaf((float)pil[3 * m + 1] + 0.5f, PSIZE, YMIN);
  }
  while (__ballot(p >= 0)) {
    if (p >= 0) {
      float x = xyz[3 * p], y = xyz[3 * p + 1], z = xyz[3 * p + 2];  // broadcast
      float h = (x - cx) * w[0];
      h = fmaf(y - cy, w[1], h);
      h = fmaf(z - CZ, w[2], h);
      h = fmaf(x, w[3], h);
      h = fmaf(y, w[4], h);
      h = fmaf(z, w[5], h);
#pragma unroll
      for (int k = 0; k < 5; k++) h = fmaf(ptf[5 * p + k], w[6 + k], h);
      v = fmaxf(fmaf(h, sc, bi), v);  // relu folded into running max (v>=0)
      p = next[p];
    }
  }
  if (m < M) out[m * CMLP + c] = v;  // coalesced; covers ALL pillars -> no memset
}

extern "C" void kernel_launch(void* const* d_in, const int* in_sizes, int n_in,
                              void* d_out, int out_size, void* d_ws, size_t ws_size,
                              hipStream_t stream) {
  const float* xyz = (const float*)d_in[0];
  const float* ptf = (const float*)d_in[1];
  const float* W1 = (const float*)d_in[2];
  const float* gamma = (const float*)d_in[3];
  const float* beta = (const float*)d_in[4];
  const int* pil = (const int*)d_in[5];
  const int* sidx = (const int*)d_in[6];
  float* out = (float*)d_out;

  int N = in_sizes[0] / 3;
  int M = in_sizes[5] / 3;

  // ws: [0,640) stats floats (77 moments; 80..111 scale; 112..143 bias)
  //     [4096, 4096+4M) head;  then next[N]
  float* stats = (float*)d_ws;
  int* head = (int*)((char*)d_ws + 4096);
  int* next = head + M;

  hipMemsetAsync(stats, 0, NMOM * sizeof(float), stream);
  hipMemsetAsync(head, 0xFF, (size_t)M * sizeof(int), stream);  // -1 sentinels

  pass1_kernel<<<1024, 256, 0, stream>>>(xyz, ptf, pil, sidx, head, next, stats, N);
  finalize_kernel<<<1, 64, 0, stream>>>(gamma, beta, W1, stats, 1.0f / (float)N);
  pool_kernel<<<(M + 7) / 8, 256, 0, stream>>>(xyz, ptf, W1, pil, head, next,
                                               stats + 80, out, M);
}

// Round 4
// 279.589 us; speedup vs baseline: 1.0819x; 1.0819x over previous
//
#include <hip/hip_runtime.h>

// PillarMaxPooling R4: moment-based BN stats + line-coalesced scatter-max.
// R3 post-mortem: random-line device atomics cost ~550B fabric traffic each
// (atomicExch list build = 486 MB, 173us). So: no per-point scattered atomics.
// K1 moments: per point, accumulate 11 first + 66 second moments of g (no
//   matmul, no atomics except 77/block). Pure 30MB read + VALU.
// K2 finalize: mean[c]=m1.W[:,c], E[h2][c]=W^T M2 W -> affine sc/bi per ch.
// K3 scatter: half-wave per point, lane=channel. 11 broadcast loads, 13 FMA,
//   ONE 32-lane atomicMax covering a single aligned 128B out row (the
//   line-coalesced pattern that made R2's scatter tolerable), no LDS.

#define CMLP 32
#define BN_EPS 1e-3f
#define PSIZE 0.075f
#define XMIN -54.0f
#define YMIN -54.0f
#define CZ   -1.0f   // 0.5*(Z_MIN+Z_MAX)
#define NMOM 77      // 11 first + 66 upper-tri second moments

__global__ void __launch_bounds__(256) moments_kernel(
    const float* __restrict__ xyz, const float* __restrict__ ptf,
    const int* __restrict__ pil, const int* __restrict__ sidx,
    float* __restrict__ stats, int N) {
  float mom[NMOM];
#pragma unroll
  for (int k = 0; k < NMOM; k++) mom[k] = 0.f;
  const int stride = gridDim.x * blockDim.x;
  for (int p = blockIdx.x * blockDim.x + threadIdx.x; p < N; p += stride) {
    int m = sidx[p];
    float cx = fmaf((float)pil[3 * m + 2] + 0.5f, PSIZE, XMIN);
    float cy = fmaf((float)pil[3 * m + 1] + 0.5f, PSIZE, YMIN);
    float x = xyz[3 * p], y = xyz[3 * p + 1], z = xyz[3 * p + 2];
    float g[11];
    g[0] = x - cx; g[1] = y - cy; g[2] = z - CZ;
    g[3] = x; g[4] = y; g[5] = z;
#pragma unroll
    for (int k = 0; k < 5; k++) g[6 + k] = ptf[5 * p + k];
    int t = 0;
#pragma unroll
    for (int i = 0; i < 11; i++) { mom[t] += g[i]; t++; }
#pragma unroll
    for (int i = 0; i < 11; i++)
#pragma unroll
      for (int j = i; j < 11; j++) { mom[t] = fmaf(g[i], g[j], mom[t]); t++; }
  }
  // wave butterfly (static indices -> registers), then block stage, 77 atomics/block
#pragma unroll
  for (int d = 1; d < 64; d <<= 1)
#pragma unroll
    for (int k = 0; k < NMOM; k++) mom[k] += __shfl_xor(mom[k], d);
  __shared__ float smom[4 * NMOM];
  const int wave = threadIdx.x >> 6;
  if ((threadIdx.x & 63) == 0) {
#pragma unroll
    for (int k = 0; k < NMOM; k++) smom[wave * NMOM + k] = mom[k];
  }
  __syncthreads();
  if (threadIdx.x < NMOM) {
    float s = smom[threadIdx.x] + smom[NMOM + threadIdx.x] +
              smom[2 * NMOM + threadIdx.x] + smom[3 * NMOM + threadIdx.x];
    atomicAdd(&stats[threadIdx.x], s);
  }
}

__global__ void finalize_kernel(const float* __restrict__ gamma,
                                const float* __restrict__ beta,
                                const float* __restrict__ W1,
                                float* __restrict__ stats, float invN) {
  int c = threadIdx.x;
  if (c < CMLP) {
    float wv[11];
#pragma unroll
    for (int k = 0; k < 11; k++) wv[k] = W1[k * CMLP + c];
    float mean = 0.f;
#pragma unroll
    for (int k = 0; k < 11; k++) mean = fmaf(wv[k], stats[k], mean);
    mean *= invN;
    float e2 = 0.f;
    int t = 11;
#pragma unroll
    for (int i = 0; i < 11; i++)
#pragma unroll
      for (int j = i; j < 11; j++) {
        float coef = (i == j) ? 1.f : 2.f;
        e2 = fmaf(coef * wv[i] * wv[j], stats[t], e2);
        t++;
      }
    e2 *= invN;
    float var = e2 - mean * mean;                 // biased, like jnp.var
    float sc = gamma[c] * rsqrtf(var + BN_EPS);
    stats[80 + c] = sc;                           // scale
    stats[112 + c] = beta[c] - mean * sc;         // bias
  }
}

__global__ void __launch_bounds__(256) scatter_kernel(
    const float* __restrict__ xyz, const float* __restrict__ ptf,
    const float* __restrict__ W1, const int* __restrict__ pil,
    const int* __restrict__ sidx, const float* __restrict__ affine,
    float* __restrict__ out, int N) {
  const int c = threadIdx.x & 31;
  float w[11];
#pragma unroll
  for (int k = 0; k < 11; k++) w[k] = W1[k * CMLP + c];
  const float sc = affine[c];
  const float bi = affine[CMLP + c];
  // half-wave per point; all 32 lanes issue the same addresses -> HW broadcast
  const int hw0 = (blockIdx.x * blockDim.x + threadIdx.x) >> 5;
  const int nhw = (gridDim.x * blockDim.x) >> 5;
  for (int p = hw0; p < N; p += nhw) {
    int m = sidx[p];
    float cx = fmaf((float)pil[3 * m + 2] + 0.5f, PSIZE, XMIN);
    float cy = fmaf((float)pil[3 * m + 1] + 0.5f, PSIZE, YMIN);
    float x = xyz[3 * p], y = xyz[3 * p + 1], z = xyz[3 * p + 2];
    float h = (x - cx) * w[0];
    h = fmaf(y - cy, w[1], h);
    h = fmaf(z - CZ, w[2], h);
    h = fmaf(x, w[3], h);
    h = fmaf(y, w[4], h);
    h = fmaf(z, w[5], h);
#pragma unroll
    for (int k = 0; k < 5; k++) h = fmaf(ptf[5 * p + k], w[6 + k], h);
    float v = fmaxf(fmaf(h, sc, bi), 0.f);
    // 32 lanes hit one aligned 128B row; v>=0 & out zeroed -> int order == fp order
    atomicMax((int*)&out[m * CMLP + c], __float_as_int(v));
  }
}

extern "C" void kernel_launch(void* const* d_in, const int* in_sizes, int n_in,
                              void* d_out, int out_size, void* d_ws, size_t ws_size,
                              hipStream_t stream) {
  const float* xyz = (const float*)d_in[0];
  const float* ptf = (const float*)d_in[1];
  const float* W1 = (const float*)d_in[2];
  const float* gamma = (const float*)d_in[3];
  const float* beta = (const float*)d_in[4];
  const int* pil = (const int*)d_in[5];
  const int* sidx = (const int*)d_in[6];
  float* out = (float*)d_out;
  float* stats = (float*)d_ws;  // [0,77) moments; [80,112) scale; [112,144) bias

  int N = in_sizes[0] / 3;

  hipMemsetAsync(stats, 0, NMOM * sizeof(float), stream);
  hipMemsetAsync(out, 0, (size_t)out_size * sizeof(float), stream);

  moments_kernel<<<768, 256, 0, stream>>>(xyz, ptf, pil, sidx, stats, N);
  finalize_kernel<<<1, 64, 0, stream>>>(gamma, beta, W1, stats, 1.0f / (float)N);
  scatter_kernel<<<4096, 256, 0, stream>>>(xyz, ptf, W1, pil, sidx, stats + 80,
                                           out, N);
}

// Round 5
// 275.045 us; speedup vs baseline: 1.0998x; 1.0165x over previous
//
#include <hip/hip_runtime.h>

// PillarMaxPooling R5: R4 + spill fix + read-filtered scatter atomics.
// R4 post-mortem: moments_kernel had VGPR_Count=60 (compiler targeted 8
// waves/EU) and spilled mom[77] -> 350 MB scratch traffic, 122us.
// __launch_bounds__(256,4) allows 128 VGPR/thread; mom[77]+g[11] fits.
// Scatter: plain load + compare before atomicMax (max is monotone ->
// stale read can only cause a redundant atomic, never a wrong skip);
// cuts ~60% of the 25.6M lane-atomics for random point order.

#define CMLP 32
#define BN_EPS 1e-3f
#define PSIZE 0.075f
#define XMIN -54.0f
#define YMIN -54.0f
#define CZ   -1.0f   // 0.5*(Z_MIN+Z_MAX)
#define NMOM 77      // 11 first + 66 upper-tri second moments

__global__ void __launch_bounds__(256, 4) moments_kernel(
    const float* __restrict__ xyz, const float* __restrict__ ptf,
    const int* __restrict__ pil, const int* __restrict__ sidx,
    float* __restrict__ stats, int N) {
  float mom[NMOM];
#pragma unroll
  for (int k = 0; k < NMOM; k++) mom[k] = 0.f;
  const int stride = gridDim.x * blockDim.x;
  for (int p = blockIdx.x * blockDim.x + threadIdx.x; p < N; p += stride) {
    int m = sidx[p];
    float cx = fmaf((float)pil[3 * m + 2] + 0.5f, PSIZE, XMIN);
    float cy = fmaf((float)pil[3 * m + 1] + 0.5f, PSIZE, YMIN);
    float x = xyz[3 * p], y = xyz[3 * p + 1], z = xyz[3 * p + 2];
    float g[11];
    g[0] = x - cx; g[1] = y - cy; g[2] = z - CZ;
    g[3] = x; g[4] = y; g[5] = z;
#pragma unroll
    for (int k = 0; k < 5; k++) g[6 + k] = ptf[5 * p + k];
    int t = 0;
#pragma unroll
    for (int i = 0; i < 11; i++) { mom[t] += g[i]; t++; }
#pragma unroll
    for (int i = 0; i < 11; i++)
#pragma unroll
      for (int j = i; j < 11; j++) { mom[t] = fmaf(g[i], g[j], mom[t]); t++; }
  }
  // wave butterfly (static indices -> registers), block stage, 77 atomics/block
#pragma unroll
  for (int d = 1; d < 64; d <<= 1)
#pragma unroll
    for (int k = 0; k < NMOM; k++) mom[k] += __shfl_xor(mom[k], d);
  __shared__ float smom[4 * NMOM];
  const int wave = threadIdx.x >> 6;
  if ((threadIdx.x & 63) == 0) {
#pragma unroll
    for (int k = 0; k < NMOM; k++) smom[wave * NMOM + k] = mom[k];
  }
  __syncthreads();
  if (threadIdx.x < NMOM) {
    float s = smom[threadIdx.x] + smom[NMOM + threadIdx.x] +
              smom[2 * NMOM + threadIdx.x] + smom[3 * NMOM + threadIdx.x];
    atomicAdd(&stats[threadIdx.x], s);
  }
}

__global__ void finalize_kernel(const float* __restrict__ gamma,
                                const float* __restrict__ beta,
                                const float* __restrict__ W1,
                                float* __restrict__ stats, float invN) {
  int c = threadIdx.x;
  if (c < CMLP) {
    float wv[11];
#pragma unroll
    for (int k = 0; k < 11; k++) wv[k] = W1[k * CMLP + c];
    float mean = 0.f;
#pragma unroll
    for (int k = 0; k < 11; k++) mean = fmaf(wv[k], stats[k], mean);
    mean *= invN;
    float e2 = 0.f;
    int t = 11;
#pragma unroll
    for (int i = 0; i < 11; i++)
#pragma unroll
      for (int j = i; j < 11; j++) {
        float coef = (i == j) ? 1.f : 2.f;
        e2 = fmaf(coef * wv[i] * wv[j], stats[t], e2);
        t++;
      }
    e2 *= invN;
    float var = e2 - mean * mean;                 // biased, like jnp.var
    float sc = gamma[c] * rsqrtf(var + BN_EPS);
    stats[80 + c] = sc;                           // scale
    stats[112 + c] = beta[c] - mean * sc;         // bias
  }
}

__global__ void __launch_bounds__(256) scatter_kernel(
    const float* __restrict__ xyz, const float* __restrict__ ptf,
    const float* __restrict__ W1, const int* __restrict__ pil,
    const int* __restrict__ sidx, const float* __restrict__ affine,
    float* __restrict__ out, int N) {
  const int c = threadIdx.x & 31;
  float w[11];
#pragma unroll
  for (int k = 0; k < 11; k++) w[k] = W1[k * CMLP + c];
  const float sc = affine[c];
  const float bi = affine[CMLP + c];
  // half-wave per point; all 32 lanes issue the same addresses -> HW broadcast
  const int hw0 = (blockIdx.x * blockDim.x + threadIdx.x) >> 5;
  const int nhw = (gridDim.x * blockDim.x) >> 5;
  for (int p = hw0; p < N; p += nhw) {
    int m = sidx[p];
    float cx = fmaf((float)pil[3 * m + 2] + 0.5f, PSIZE, XMIN);
    float cy = fmaf((float)pil[3 * m + 1] + 0.5f, PSIZE, YMIN);
    float x = xyz[3 * p], y = xyz[3 * p + 1], z = xyz[3 * p + 2];
    float h = (x - cx) * w[0];
    h = fmaf(y - cy, w[1], h);
    h = fmaf(z - CZ, w[2], h);
    h = fmaf(x, w[3], h);
    h = fmaf(y, w[4], h);
    h = fmaf(z, w[5], h);
#pragma unroll
    for (int k = 0; k < 5; k++) h = fmaf(ptf[5 * p + k], w[6 + k], h);
    float v = fmaxf(fmaf(h, sc, bi), 0.f);
    // read-filter: max is monotone, so a stale read only causes a redundant
    // atomic, never a wrong skip. v>=0 & out zeroed -> int order == fp order.
    int* addr = (int*)&out[m * CMLP + c];
    if (__float_as_int(v) > *addr) atomicMax(addr, __float_as_int(v));
  }
}

extern "C" void kernel_launch(void* const* d_in, const int* in_sizes, int n_in,
                              void* d_out, int out_size, void* d_ws, size_t ws_size,
                              hipStream_t stream) {
  const float* xyz = (const float*)d_in[0];
  const float* ptf = (const float*)d_in[1];
  const float* W1 = (const float*)d_in[2];
  const float* gamma = (const float*)d_in[3];
  const float* beta = (const float*)d_in[4];
  const int* pil = (const int*)d_in[5];
  const int* sidx = (const int*)d_in[6];
  float* out = (float*)d_out;
  float* stats = (float*)d_ws;  // [0,77) moments; [80,112) scale; [112,144) bias

  int N = in_sizes[0] / 3;

  hipMemsetAsync(stats, 0, NMOM * sizeof(float), stream);
  hipMemsetAsync(out, 0, (size_t)out_size * sizeof(float), stream);

  moments_kernel<<<768, 256, 0, stream>>>(xyz, ptf, pil, sidx, stats, N);
  finalize_kernel<<<1, 64, 0, stream>>>(gamma, beta, W1, stats, 1.0f / (float)N);
  scatter_kernel<<<4096, 256, 0, stream>>>(xyz, ptf, W1, pil, sidx, stats + 80,
                                           out, N);
}